// Round 1
// 406.143 us; speedup vs baseline: 1.0806x; 1.0806x over previous
//
#include <hip/hip_runtime.h>

// FFT-conv: y = real(ifft2( sum_i K[o,i] * fft2(x[b,i]) )) + bias
// B=32, CIN=64, COUT=128, H=W=56.
// Hermitian symmetry: only spectral rows kh=0..28 stored (NFH=1624 bins).
// Pipeline:
//   kprep : K fp32 [o][i][f] -> bf16 planes [f][o][i]   (LDS transpose)
//   kfwd  : forward FFT2 per (b,i) image, bf16 MFMA, writes bf16 ushort2
//   kmix  : per-bin complex channel mix as bf16 MFMA GEMM (M=32,N=128,K=64)
//   kinv  : inverse FFT2 per (b,o), bf16 MFMA (reads bf16 Y directly)

#define HH 56
#define NF 3136      // 56*56
#define KH 29        // stored spectral rows
#define NFH 1624     // 29*56
constexpr int B = 32, CIN = 64, COUT = 128;
constexpr float PI2 = 6.283185307179586f;

typedef unsigned short u16;
typedef __attribute__((ext_vector_type(8))) short s8v;   // 8 x bf16 (A/B frag)
typedef __attribute__((ext_vector_type(4))) float f4v;   // C/D frag
typedef __attribute__((ext_vector_type(4))) int i4v;

#define MFMA(a, b, c) __builtin_amdgcn_mfma_f32_16x16x32_bf16(a, b, c, 0, 0, 0)

__device__ __host__ inline short f2bf(float f) {
    unsigned u = __builtin_bit_cast(unsigned, f);
    u += 0x7fffu + ((u >> 16) & 1u);      // round-to-nearest-even
    return (short)(u >> 16);
}

__device__ inline s8v negbf(s8v a) {       // flip bf16 sign bits
    i4v t = __builtin_bit_cast(i4v, a);
    t ^= (int)0x80008000u;
    return __builtin_bit_cast(s8v, t);
}

// ---------------------------------------------------------------------------
// Constant pool in d_ws (shorts):
//   Cw  [64][72] @0     : cos(2*pi*m*n/56), m<56&&n<56 else 0   (symmetric)
//   Sw  [64][72] @4608  : +sin(...)                             (symmetric)
//   SwN [64][72] @9216  : -sin(...)
//   A2C [64][40] @13824 : wgt(kh)*cos(2*pi*h*kh/56)/3136  (h<56,kh<29 else 0)
//   A2S [64][40] @16384 : -wgt(kh)*sin(...)/3136
__global__ __launch_bounds__(256) void ksetup(short* __restrict__ cpool) {
    int i = blockIdx.x * 256 + threadIdx.x;
    if (i < 4608) {
        int m = i / 72, n = i % 72;
        float c = 0.f, s = 0.f;
        if (m < 56 && n < 56) {
            float ang = PI2 * (float)((m * n) % 56) / 56.f;
            c = cosf(ang); s = sinf(ang);
        }
        cpool[i]        = f2bf(c);
        cpool[4608 + i] = f2bf(s);
        cpool[9216 + i] = f2bf(-s);
    } else if (i < 7168) {
        int j = i - 4608;
        int h = j / 40, kh = j % 40;
        float c = 0.f, s = 0.f;
        if (h < 56 && kh < 29) {
            float w = (kh == 0 || kh == 28) ? 1.f : 2.f;
            float ang = PI2 * (float)((h * kh) % 56) / 56.f;
            float sc = w * (1.f / 3136.f);
            c = sc * cosf(ang);
            s = -sc * sinf(ang);
        }
        cpool[13824 + j] = f2bf(c);
        cpool[16384 + j] = f2bf(s);
    }
}

// ---------------------------------------------------------------------------
// kprep: repack K spectrum fp32 [o][i][3136] (first 1624 bins used) into
// bf16 planes Kbr/Kbi [f][o*64+i] so kmix B-fragments are contiguous.
// Block = 64 consecutive (o,i) rows x 56 bins; LDS transpose [row][f]->[f][row].
__global__ __launch_bounds__(256) void kprep(const float* __restrict__ Kr,
                                             const float* __restrict__ Ki,
                                             u16* __restrict__ Kbr,
                                             u16* __restrict__ Kbi) {
    __shared__ u16 Lr[64 * 57], Li[64 * 57];
    const int tid = threadIdx.x;
    const int oi0 = blockIdx.x * 64;   // 8192/64 = 128 tiles
    const int f0  = blockIdx.y * 56;   // 1624/56 = 29 tiles
    for (int idx = tid; idx < 3584; idx += 256) {     // 64*56
        int row = idx / 56, f = idx % 56;
        size_t g = (size_t)(oi0 + row) * NF + f0 + f;
        Lr[row * 57 + f] = (u16)f2bf(Kr[g]);
        Li[row * 57 + f] = (u16)f2bf(Ki[g]);
    }
    __syncthreads();
    for (int idx = tid; idx < 3584; idx += 256) {
        int f = idx >> 6, j = idx & 63;               // j fastest -> 128B/f contiguous
        size_t o = (size_t)(f0 + f) * 8192 + oi0 + j;
        Kbr[o] = Lr[j * 57 + f];
        Kbi[o] = Li[j * 57 + f];
    }
}

// ---------------------------------------------------------------------------
// Kernel A: forward FFT2 per (b,i) image via two MFMA GEMM passes.
//   stage1: S1[h][kw]  = sum_w  x[h][w] * e^{-2pi i w kw/56}
//   stage2: X[kh][kw]  = sum_h  e^{-2pi i h kh/56} * S1[h][kw]   (kh<29 stored)
// Output: bf16 ushort2 (r,i) at [b*CIN+i][kh*56+kw].
__global__ __launch_bounds__(256) void kfwd(const float* __restrict__ x,
                                            const short* __restrict__ cpool,
                                            ushort2* __restrict__ Xb) {
    __shared__ __align__(16) short Cw[4608], Sw[4608], SwN[4608];
    __shared__ __align__(16) short xs[4608];            // [h][72] bf16
    __shared__ __align__(16) short T1r[4608], T1i[4608]; // S1 transposed [kw][72]
    const int tid = threadIdx.x;
    {
        const int4* src = (const int4*)cpool;
        for (int i = tid; i < 576; i += 256) {
            ((int4*)Cw)[i]  = src[i];
            ((int4*)Sw)[i]  = src[576 + i];
            ((int4*)SwN)[i] = src[1152 + i];
        }
    }
    for (int i = tid; i < 2304; i += 256) ((int*)xs)[i] = 0;
    __syncthreads();
    const float* xp = x + (size_t)blockIdx.x * NF;
    for (int i = tid; i < NF; i += 256) {
        int h = i / 56, w = i % 56;
        xs[h * 72 + w] = f2bf(xp[i]);
    }
    __syncthreads();

    const int lane = tid & 63;
    const int nt = tid >> 6;            // wave = N-tile strip
    const int q = lane >> 4, l15 = lane & 15;

    // ---- stage 1: A = xs[h][w], B = (C - iS)[w][kw]  (B read via symmetry)
    f4v aR[4] = {}, aI[4] = {};
    for (int ks = 0; ks < 2; ++ks) {
        const int bo = (nt * 16 + l15) * 72 + ks * 32 + q * 8;
        s8v bC = *(const s8v*)&Cw[bo];
        s8v bS = *(const s8v*)&SwN[bo];
        for (int mt = 0; mt < 4; ++mt) {
            s8v a = *(const s8v*)&xs[(mt * 16 + l15) * 72 + ks * 32 + q * 8];
            aR[mt] = MFMA(a, bC, aR[mt]);
            aI[mt] = MFMA(a, bS, aI[mt]);
        }
    }
    for (int mt = 0; mt < 4; ++mt)
        for (int r = 0; r < 4; ++r) {
            int o = (nt * 16 + l15) * 72 + mt * 16 + q * 4 + r;  // [kw][h]
            T1r[o] = f2bf(aR[mt][r]);
            T1i[o] = f2bf(aI[mt][r]);
        }
    __syncthreads();

    // ---- stage 2: A = (C2|S2)[kh][h] (top 32 rows of Cw/Sw), B = S1[h][kw]
    //      Xr = C2*S1r + S2*S1i ;  Xi = C2*S1i - S2*S1r
    f4v xr[2] = {}, xi2[2] = {};
    for (int ks = 0; ks < 2; ++ks) {
        const int bo = (nt * 16 + l15) * 72 + ks * 32 + q * 8;
        s8v br = *(const s8v*)&T1r[bo];
        s8v bi = *(const s8v*)&T1i[bo];
        for (int mt = 0; mt < 2; ++mt) {
            const int ao = (mt * 16 + l15) * 72 + ks * 32 + q * 8;
            s8v aC  = *(const s8v*)&Cw[ao];
            s8v aS  = *(const s8v*)&Sw[ao];
            s8v aSN = *(const s8v*)&SwN[ao];
            xr[mt]  = MFMA(aC, br, xr[mt]);
            xr[mt]  = MFMA(aS, bi, xr[mt]);
            xi2[mt] = MFMA(aC, bi, xi2[mt]);
            xi2[mt] = MFMA(aSN, br, xi2[mt]);
        }
    }
    ushort2* op = Xb + (size_t)blockIdx.x * NFH;
    const int kw = nt * 16 + l15;
    if (kw < 56) {
        for (int mt = 0; mt < 2; ++mt)
            for (int r = 0; r < 4; ++r) {
                int kh = mt * 16 + q * 4 + r;
                if (kh < 29)
                    op[kh * 56 + kw] = make_ushort2((u16)f2bf(xr[mt][r]),
                                                    (u16)f2bf(xi2[mt][r]));
            }
    }
}

// ---------------------------------------------------------------------------
// kmix: per-bin complex channel mix as bf16 MFMA GEMM.
//   Y[b][o](f) = sum_i X[b][i](f) * K[o][i](f)
// Block = 8 consecutive bins (grid 203), 512 threads = 8 waves.
// X staged once into padded LDS planes [8][32][72] (144B rows: conflict-free
// b128 frag reads). K B-frags read directly from global [f][o][i] planes
// (full-granule, fetched exactly once). Complex product = 4 MFMAs with a
// sign-flipped -Xi fragment.
__global__ __launch_bounds__(512) void kmix(const ushort2* __restrict__ Xb,
                                            const u16* __restrict__ Kbr,
                                            const u16* __restrict__ Kbi,
                                            ushort2* __restrict__ Yb) {
    __shared__ __align__(16) u16 Xr[8 * 2304], Xi[8 * 2304];  // [f][b][72]
    const int tid = threadIdx.x;
    const int f0 = blockIdx.x * 8;

    // ---- stage X: 2048 (b,i) rows x 8 bins (2 x uint4 = 32B each)
    for (int rr = 0; rr < 4; ++rr) {
        int row = rr * 512 + tid;                       // b*64+i
        const uint4* src = (const uint4*)(Xb + (size_t)row * NFH + f0);
        uint4 v0 = src[0], v1 = src[1];
        int base = (row >> 6) * 72 + (row & 63);
        unsigned uu[8] = {v0.x, v0.y, v0.z, v0.w, v1.x, v1.y, v1.z, v1.w};
        #pragma unroll
        for (int ff = 0; ff < 8; ++ff) {
            Xr[ff * 2304 + base] = (u16)uu[ff];
            Xi[ff * 2304 + base] = (u16)(uu[ff] >> 16);
        }
    }
    __syncthreads();

    const int lane = tid & 63;
    const int wv = tid >> 6;            // wave = o-tile (8 x 16 = 128 outs)
    const int q = lane >> 4, l15 = lane & 15;

    for (int ff = 0; ff < 8; ++ff) {
        const int f = f0 + ff;
        // B-frags direct from global: K[f][o][i], lane l15 -> o, q*8 -> i
        const size_t kb = (size_t)f * 8192 + (size_t)(wv * 16 + l15) * 64 + q * 8;
        s8v bkr0 = *(const s8v*)&Kbr[kb];
        s8v bkr1 = *(const s8v*)&Kbr[kb + 32];
        s8v bki0 = *(const s8v*)&Kbi[kb];
        s8v bki1 = *(const s8v*)&Kbi[kb + 32];

        f4v yr[2] = {}, yi[2] = {};
        #pragma unroll
        for (int mt = 0; mt < 2; ++mt) {
            const int ao = ff * 2304 + (mt * 16 + l15) * 72 + q * 8;
            s8v axr0 = *(const s8v*)&Xr[ao];
            s8v axr1 = *(const s8v*)&Xr[ao + 32];
            s8v axi0 = *(const s8v*)&Xi[ao];
            s8v axi1 = *(const s8v*)&Xi[ao + 32];
            s8v axn0 = negbf(axi0), axn1 = negbf(axi1);
            yr[mt] = MFMA(axr0, bkr0, yr[mt]);   // Yr = Xr*Kr - Xi*Ki
            yr[mt] = MFMA(axn0, bki0, yr[mt]);
            yr[mt] = MFMA(axr1, bkr1, yr[mt]);
            yr[mt] = MFMA(axn1, bki1, yr[mt]);
            yi[mt] = MFMA(axr0, bki0, yi[mt]);   // Yi = Xr*Ki + Xi*Kr
            yi[mt] = MFMA(axi0, bkr0, yi[mt]);
            yi[mt] = MFMA(axr1, bki1, yi[mt]);
            yi[mt] = MFMA(axi1, bkr1, yi[mt]);
        }
        const int o = wv * 16 + l15;
        #pragma unroll
        for (int mt = 0; mt < 2; ++mt)
            #pragma unroll
            for (int r = 0; r < 4; ++r) {
                int b = mt * 16 + q * 4 + r;
                Yb[(size_t)(b * COUT + o) * NFH + f] =
                    make_ushort2((u16)f2bf(yr[mt][r]), (u16)f2bf(yi[mt][r]));
            }
    }
}

// ---------------------------------------------------------------------------
// Kernel C: inverse FFT2 per (b,o) image via two MFMA GEMM passes + fold.
//   inv1: Z[kh][w] = sum_kw Y[kh][kw] * e^{+2pi i kw w/56}
//   inv2: y[h][w]  = sum_kh wgt(kh)*(Zr*cos - Zi*sin)/3136 + bias
// Input Y is bf16 ushort2 — no conversion needed for staging.
__global__ __launch_bounds__(256) void kinv(const ushort2* __restrict__ Yf,
                                            const short* __restrict__ cpool,
                                            const float* __restrict__ bias,
                                            float* __restrict__ out) {
    __shared__ __align__(16) short Cw[4608], Sw[4608], SwN[4608];
    __shared__ __align__(16) short A2C[2560], A2S[2560];
    __shared__ __align__(16) short Yr[2304], Yi[2304];   // [kh][72]
    __shared__ __align__(16) short ZTr[2560], ZTi[2560]; // Z transposed [w][40]
    const int tid = threadIdx.x;
    {
        const int4* src = (const int4*)cpool;
        for (int i = tid; i < 576; i += 256) {
            ((int4*)Cw)[i]  = src[i];
            ((int4*)Sw)[i]  = src[576 + i];
            ((int4*)SwN)[i] = src[1152 + i];
        }
        for (int i = tid; i < 320; i += 256) {
            ((int4*)A2C)[i] = src[1728 + i];
            ((int4*)A2S)[i] = src[2048 + i];
        }
    }
    for (int i = tid; i < 1152; i += 256) { ((int*)Yr)[i] = 0; ((int*)Yi)[i] = 0; }
    __syncthreads();
    const ushort2* yp = Yf + (size_t)blockIdx.x * NFH;
    for (int f = tid; f < NFH; f += 256) {
        int kh = f / 56, kw = f % 56;
        ushort2 v = yp[f];
        Yr[kh * 72 + kw] = (short)v.x;
        Yi[kh * 72 + kw] = (short)v.y;
    }
    __syncthreads();

    const int lane = tid & 63;
    const int nt = tid >> 6;
    const int q = lane >> 4, l15 = lane & 15;

    // ---- inv1: A = Y[kh][kw], B = (C + iS)[kw][w] via symmetry
    //      Zr = Yr*C - Yi*S ;  Zi = Yr*S + Yi*C
    f4v zr[2] = {}, zi[2] = {};
    for (int ks = 0; ks < 2; ++ks) {
        const int bo = (nt * 16 + l15) * 72 + ks * 32 + q * 8;
        s8v bC  = *(const s8v*)&Cw[bo];
        s8v bS  = *(const s8v*)&Sw[bo];
        s8v bSN = *(const s8v*)&SwN[bo];
        for (int mt = 0; mt < 2; ++mt) {
            const int ao = (mt * 16 + l15) * 72 + ks * 32 + q * 8;
            s8v ar = *(const s8v*)&Yr[ao];
            s8v ai = *(const s8v*)&Yi[ao];
            zr[mt] = MFMA(ar, bC, zr[mt]);
            zr[mt] = MFMA(ai, bSN, zr[mt]);
            zi[mt] = MFMA(ar, bS, zi[mt]);
            zi[mt] = MFMA(ai, bC, zi[mt]);
        }
    }
    for (int mt = 0; mt < 2; ++mt)
        for (int r = 0; r < 4; ++r) {
            int o = (nt * 16 + l15) * 40 + mt * 16 + q * 4 + r;  // [w][kh]
            ZTr[o] = f2bf(zr[mt][r]);
            ZTi[o] = f2bf(zi[mt][r]);
        }
    __syncthreads();

    // ---- inv2: A = A2C/A2S [h][kh] (K=32, one k-step), B = Z[kh][w]
    f4v yv[4] = {};
    {
        const int bo = (nt * 16 + l15) * 40 + q * 8;
        s8v br = *(const s8v*)&ZTr[bo];
        s8v bi = *(const s8v*)&ZTi[bo];
        for (int mt = 0; mt < 4; ++mt) {
            const int ao = (mt * 16 + l15) * 40 + q * 8;
            s8v ac  = *(const s8v*)&A2C[ao];
            s8v as_ = *(const s8v*)&A2S[ao];
            yv[mt] = MFMA(ac, br, yv[mt]);
            yv[mt] = MFMA(as_, bi, yv[mt]);
        }
    }
    const float bv = bias[blockIdx.x & (COUT - 1)];
    float* opx = out + (size_t)blockIdx.x * NF;
    const int w = nt * 16 + l15;
    if (w < 56) {
        for (int mt = 0; mt < 4; ++mt)
            for (int r = 0; r < 4; ++r) {
                int h = mt * 16 + q * 4 + r;
                if (h < 56) opx[h * 56 + w] = yv[mt][r] + bv;
            }
    }
}

// ---------------------------------------------------------------------------
extern "C" void kernel_launch(void* const* d_in, const int* in_sizes, int n_in,
                              void* d_out, int out_size, void* d_ws, size_t ws_size,
                              hipStream_t stream) {
    const float* x    = (const float*)d_in[0];
    const float* Kr   = (const float*)d_in[1];
    const float* Ki   = (const float*)d_in[2];
    const float* bias = (const float*)d_in[3];

    // Workspace layout (93.2 MB total):
    //   cpool  @0          : 40960 B constants
    //   Xb     @40960      : bf16 [B][CIN][1624]  ushort2   13,307,904 B
    //   Yb     @+13307904  : bf16 [B][COUT][1624] ushort2   26,615,808 B
    //   Kbr    @+26615808  : bf16 [1624][8192]               26,615,808 B
    //   Kbi    @+26615808  : bf16 [1624][8192]               26,615,808 B
    short*   cpool = (short*)d_ws;
    ushort2* Xb  = (ushort2*)((char*)d_ws + 40960);
    ushort2* Yb  = (ushort2*)((char*)d_ws + 40960 + 13307904);
    u16*     Kbr = (u16*)((char*)d_ws + 40960 + 13307904 + 26615808);
    u16*     Kbi = Kbr + (size_t)13307904;

    hipLaunchKernelGGL(ksetup, dim3(28), dim3(256), 0, stream, cpool);
    hipLaunchKernelGGL(kprep, dim3(128, 29), dim3(256), 0, stream, Kr, Ki, Kbr, Kbi);
    hipLaunchKernelGGL(kfwd, dim3(B * CIN), dim3(256), 0, stream, x, cpool, Xb);
    hipLaunchKernelGGL(kmix, dim3(NFH / 8), dim3(512), 0, stream, Xb, Kbr, Kbi, Yb);
    hipLaunchKernelGGL(kinv, dim3(B * COUT), dim3(256), 0, stream,
                       Yb, cpool, bias, (float*)d_out);
}

// Round 2
// 343.688 us; speedup vs baseline: 1.2769x; 1.1817x over previous
//
#include <hip/hip_runtime.h>

// FFT-conv: y = real(ifft2( sum_i K[o,i] * fft2(x[b,i]) )) + bias
// B=32, CIN=64, COUT=128, H=W=56.
// Hermitian symmetry: only spectral rows kh=0..28 stored (NFH=1624 bins).
// Pipeline:
//   kprep : K fp32 [o][i][f] -> bf16 planes [f][o][i]   (LDS transpose)
//   kfwd  : forward FFT2 per (b,i) image, bf16 MFMA, writes bf16 ushort2
//   kmix  : per-bin complex channel mix as bf16 MFMA GEMM (M=32,N=128,K=64)
//           output kept in registers, written as 32B aligned bursts
//   kinv  : inverse FFT2 per (b,o), bf16 MFMA (reads bf16 Y directly)

#define HH 56
#define NF 3136      // 56*56
#define KH 29        // stored spectral rows
#define NFH 1624     // 29*56
constexpr int B = 32, CIN = 64, COUT = 128;
constexpr float PI2 = 6.283185307179586f;

typedef unsigned short u16;
typedef __attribute__((ext_vector_type(8))) short s8v;   // 8 x bf16 (A/B frag)
typedef __attribute__((ext_vector_type(4))) float f4v;   // C/D frag
typedef __attribute__((ext_vector_type(4))) int i4v;

#define MFMA(a, b, c) __builtin_amdgcn_mfma_f32_16x16x32_bf16(a, b, c, 0, 0, 0)

__device__ __host__ inline short f2bf(float f) {
    unsigned u = __builtin_bit_cast(unsigned, f);
    u += 0x7fffu + ((u >> 16) & 1u);      // round-to-nearest-even
    return (short)(u >> 16);
}

__device__ inline s8v negbf(s8v a) {       // flip bf16 sign bits
    i4v t = __builtin_bit_cast(i4v, a);
    t ^= (int)0x80008000u;
    return __builtin_bit_cast(s8v, t);
}

// ---------------------------------------------------------------------------
// Constant pool in d_ws (shorts):
//   Cw  [64][72] @0     : cos(2*pi*m*n/56), m<56&&n<56 else 0   (symmetric)
//   Sw  [64][72] @4608  : +sin(...)                             (symmetric)
//   SwN [64][72] @9216  : -sin(...)
//   A2C [64][40] @13824 : wgt(kh)*cos(2*pi*h*kh/56)/3136  (h<56,kh<29 else 0)
//   A2S [64][40] @16384 : -wgt(kh)*sin(...)/3136
__global__ __launch_bounds__(256) void ksetup(short* __restrict__ cpool) {
    int i = blockIdx.x * 256 + threadIdx.x;
    if (i < 4608) {
        int m = i / 72, n = i % 72;
        float c = 0.f, s = 0.f;
        if (m < 56 && n < 56) {
            float ang = PI2 * (float)((m * n) % 56) / 56.f;
            c = cosf(ang); s = sinf(ang);
        }
        cpool[i]        = f2bf(c);
        cpool[4608 + i] = f2bf(s);
        cpool[9216 + i] = f2bf(-s);
    } else if (i < 7168) {
        int j = i - 4608;
        int h = j / 40, kh = j % 40;
        float c = 0.f, s = 0.f;
        if (h < 56 && kh < 29) {
            float w = (kh == 0 || kh == 28) ? 1.f : 2.f;
            float ang = PI2 * (float)((h * kh) % 56) / 56.f;
            float sc = w * (1.f / 3136.f);
            c = sc * cosf(ang);
            s = -sc * sinf(ang);
        }
        cpool[13824 + j] = f2bf(c);
        cpool[16384 + j] = f2bf(s);
    }
}

// ---------------------------------------------------------------------------
// kprep: repack K spectrum fp32 [o][i][3136] (first 1624 bins used) into
// bf16 planes Kbr/Kbi [f][o*64+i] so kmix B-fragments are contiguous.
// Block = 64 consecutive (o,i) rows x 56 bins; LDS transpose [row][f]->[f][row].
__global__ __launch_bounds__(256) void kprep(const float* __restrict__ Kr,
                                             const float* __restrict__ Ki,
                                             u16* __restrict__ Kbr,
                                             u16* __restrict__ Kbi) {
    __shared__ u16 Lr[64 * 57], Li[64 * 57];
    const int tid = threadIdx.x;
    const int oi0 = blockIdx.x * 64;   // 8192/64 = 128 tiles
    const int f0  = blockIdx.y * 56;   // 1624/56 = 29 tiles
    for (int idx = tid; idx < 3584; idx += 256) {     // 64*56
        int row = idx / 56, f = idx % 56;
        size_t g = (size_t)(oi0 + row) * NF + f0 + f;
        Lr[row * 57 + f] = (u16)f2bf(Kr[g]);
        Li[row * 57 + f] = (u16)f2bf(Ki[g]);
    }
    __syncthreads();
    for (int idx = tid; idx < 3584; idx += 256) {
        int f = idx >> 6, j = idx & 63;               // j fastest -> 128B/f contiguous
        size_t o = (size_t)(f0 + f) * 8192 + oi0 + j;
        Kbr[o] = Lr[j * 57 + f];
        Kbi[o] = Li[j * 57 + f];
    }
}

// ---------------------------------------------------------------------------
// Kernel A: forward FFT2 per (b,i) image via two MFMA GEMM passes.
//   stage1: S1[h][kw]  = sum_w  x[h][w] * e^{-2pi i w kw/56}
//   stage2: X[kh][kw]  = sum_h  e^{-2pi i h kh/56} * S1[h][kw]   (kh<29 stored)
// Output: bf16 ushort2 (r,i) at [b*CIN+i][kh*56+kw].
__global__ __launch_bounds__(256) void kfwd(const float* __restrict__ x,
                                            const short* __restrict__ cpool,
                                            ushort2* __restrict__ Xb) {
    __shared__ __align__(16) short Cw[4608], Sw[4608], SwN[4608];
    __shared__ __align__(16) short xs[4608];            // [h][72] bf16
    __shared__ __align__(16) short T1r[4608], T1i[4608]; // S1 transposed [kw][72]
    const int tid = threadIdx.x;
    {
        const int4* src = (const int4*)cpool;
        for (int i = tid; i < 576; i += 256) {
            ((int4*)Cw)[i]  = src[i];
            ((int4*)Sw)[i]  = src[576 + i];
            ((int4*)SwN)[i] = src[1152 + i];
        }
    }
    for (int i = tid; i < 2304; i += 256) ((int*)xs)[i] = 0;
    __syncthreads();
    const float* xp = x + (size_t)blockIdx.x * NF;
    for (int i = tid; i < NF; i += 256) {
        int h = i / 56, w = i % 56;
        xs[h * 72 + w] = f2bf(xp[i]);
    }
    __syncthreads();

    const int lane = tid & 63;
    const int nt = tid >> 6;            // wave = N-tile strip
    const int q = lane >> 4, l15 = lane & 15;

    // ---- stage 1: A = xs[h][w], B = (C - iS)[w][kw]  (B read via symmetry)
    f4v aR[4] = {}, aI[4] = {};
    for (int ks = 0; ks < 2; ++ks) {
        const int bo = (nt * 16 + l15) * 72 + ks * 32 + q * 8;
        s8v bC = *(const s8v*)&Cw[bo];
        s8v bS = *(const s8v*)&SwN[bo];
        for (int mt = 0; mt < 4; ++mt) {
            s8v a = *(const s8v*)&xs[(mt * 16 + l15) * 72 + ks * 32 + q * 8];
            aR[mt] = MFMA(a, bC, aR[mt]);
            aI[mt] = MFMA(a, bS, aI[mt]);
        }
    }
    for (int mt = 0; mt < 4; ++mt)
        for (int r = 0; r < 4; ++r) {
            int o = (nt * 16 + l15) * 72 + mt * 16 + q * 4 + r;  // [kw][h]
            T1r[o] = f2bf(aR[mt][r]);
            T1i[o] = f2bf(aI[mt][r]);
        }
    __syncthreads();

    // ---- stage 2: A = (C2|S2)[kh][h] (top 32 rows of Cw/Sw), B = S1[h][kw]
    //      Xr = C2*S1r + S2*S1i ;  Xi = C2*S1i - S2*S1r
    f4v xr[2] = {}, xi2[2] = {};
    for (int ks = 0; ks < 2; ++ks) {
        const int bo = (nt * 16 + l15) * 72 + ks * 32 + q * 8;
        s8v br = *(const s8v*)&T1r[bo];
        s8v bi = *(const s8v*)&T1i[bo];
        for (int mt = 0; mt < 2; ++mt) {
            const int ao = (mt * 16 + l15) * 72 + ks * 32 + q * 8;
            s8v aC  = *(const s8v*)&Cw[ao];
            s8v aS  = *(const s8v*)&Sw[ao];
            s8v aSN = *(const s8v*)&SwN[ao];
            xr[mt]  = MFMA(aC, br, xr[mt]);
            xr[mt]  = MFMA(aS, bi, xr[mt]);
            xi2[mt] = MFMA(aC, bi, xi2[mt]);
            xi2[mt] = MFMA(aSN, br, xi2[mt]);
        }
    }
    ushort2* op = Xb + (size_t)blockIdx.x * NFH;
    const int kw = nt * 16 + l15;
    if (kw < 56) {
        for (int mt = 0; mt < 2; ++mt)
            for (int r = 0; r < 4; ++r) {
                int kh = mt * 16 + q * 4 + r;
                if (kh < 29)
                    op[kh * 56 + kw] = make_ushort2((u16)f2bf(xr[mt][r]),
                                                    (u16)f2bf(xi2[mt][r]));
            }
    }
}

// ---------------------------------------------------------------------------
// kmix: per-bin complex channel mix as bf16 MFMA GEMM.
//   Y[b][o](f) = sum_i X[b][i](f) * K[o][i](f)
// Block = 8 consecutive bins (grid 203), 512 threads = 8 waves.
// X staged once into padded LDS planes [8][32][72]; K B-frags read directly
// from global [f][o][i] planes (full-granule, fetched exactly once).
// Output: packed bf16 (yr|yi<<16) accumulated in registers across the 8-bin
// loop, then each thread writes one 32B-aligned 32B burst per (b,o) row
// (2x uint4) -> full-sector stores, no write amplification.
__global__ __launch_bounds__(512) void kmix(const ushort2* __restrict__ Xb,
                                            const u16* __restrict__ Kbr,
                                            const u16* __restrict__ Kbi,
                                            ushort2* __restrict__ Yb) {
    __shared__ __align__(16) u16 Xr[8 * 2304], Xi[8 * 2304];  // [f][b][72]
    const int tid = threadIdx.x;
    const int f0 = blockIdx.x * 8;

    // ---- stage X: 2048 (b,i) rows x 8 bins (2 x uint4 = 32B each)
    for (int rr = 0; rr < 4; ++rr) {
        int row = rr * 512 + tid;                       // b*64+i
        const uint4* src = (const uint4*)(Xb + (size_t)row * NFH + f0);
        uint4 v0 = src[0], v1 = src[1];
        int base = (row >> 6) * 72 + (row & 63);
        unsigned uu[8] = {v0.x, v0.y, v0.z, v0.w, v1.x, v1.y, v1.z, v1.w};
        #pragma unroll
        for (int ff = 0; ff < 8; ++ff) {
            Xr[ff * 2304 + base] = (u16)uu[ff];
            Xi[ff * 2304 + base] = (u16)(uu[ff] >> 16);
        }
    }
    __syncthreads();

    const int lane = tid & 63;
    const int wv = tid >> 6;            // wave = o-tile (8 x 16 = 128 outs)
    const int q = lane >> 4, l15 = lane & 15;

    unsigned pk[2][4][8];               // [mt][r][ff] packed (yr | yi<<16)

    #pragma unroll
    for (int ff = 0; ff < 8; ++ff) {
        const int f = f0 + ff;
        // B-frags direct from global: K[f][o][i], lane l15 -> o, q*8 -> i
        const size_t kb = (size_t)f * 8192 + (size_t)(wv * 16 + l15) * 64 + q * 8;
        s8v bkr0 = *(const s8v*)&Kbr[kb];
        s8v bkr1 = *(const s8v*)&Kbr[kb + 32];
        s8v bki0 = *(const s8v*)&Kbi[kb];
        s8v bki1 = *(const s8v*)&Kbi[kb + 32];

        f4v yr[2] = {}, yi[2] = {};
        #pragma unroll
        for (int mt = 0; mt < 2; ++mt) {
            const int ao = ff * 2304 + (mt * 16 + l15) * 72 + q * 8;
            s8v axr0 = *(const s8v*)&Xr[ao];
            s8v axr1 = *(const s8v*)&Xr[ao + 32];
            s8v axi0 = *(const s8v*)&Xi[ao];
            s8v axi1 = *(const s8v*)&Xi[ao + 32];
            s8v axn0 = negbf(axi0), axn1 = negbf(axi1);
            yr[mt] = MFMA(axr0, bkr0, yr[mt]);   // Yr = Xr*Kr - Xi*Ki
            yr[mt] = MFMA(axn0, bki0, yr[mt]);
            yr[mt] = MFMA(axr1, bkr1, yr[mt]);
            yr[mt] = MFMA(axn1, bki1, yr[mt]);
            yi[mt] = MFMA(axr0, bki0, yi[mt]);   // Yi = Xr*Ki + Xi*Kr
            yi[mt] = MFMA(axi0, bkr0, yi[mt]);
            yi[mt] = MFMA(axr1, bki1, yi[mt]);
            yi[mt] = MFMA(axi1, bkr1, yi[mt]);
        }
        #pragma unroll
        for (int mt = 0; mt < 2; ++mt)
            #pragma unroll
            for (int r = 0; r < 4; ++r)
                pk[mt][r][ff] = (unsigned)(u16)f2bf(yr[mt][r]) |
                                ((unsigned)(u16)f2bf(yi[mt][r]) << 16);
    }

    // ---- burst write: one 32B-aligned 32B run per (b,o) row
    const int o = wv * 16 + l15;
    #pragma unroll
    for (int mt = 0; mt < 2; ++mt)
        #pragma unroll
        for (int r = 0; r < 4; ++r) {
            const int b = mt * 16 + q * 4 + r;
            uint4* dst = (uint4*)(Yb + (size_t)(b * COUT + o) * NFH + f0);
            dst[0] = make_uint4(pk[mt][r][0], pk[mt][r][1],
                                pk[mt][r][2], pk[mt][r][3]);
            dst[1] = make_uint4(pk[mt][r][4], pk[mt][r][5],
                                pk[mt][r][6], pk[mt][r][7]);
        }
}

// ---------------------------------------------------------------------------
// Kernel C: inverse FFT2 per (b,o) image via two MFMA GEMM passes + fold.
//   inv1: Z[kh][w] = sum_kw Y[kh][kw] * e^{+2pi i kw w/56}
//   inv2: y[h][w]  = sum_kh wgt(kh)*(Zr*cos - Zi*sin)/3136 + bias
// Input Y is bf16 ushort2 — no conversion needed for staging.
__global__ __launch_bounds__(256) void kinv(const ushort2* __restrict__ Yf,
                                            const short* __restrict__ cpool,
                                            const float* __restrict__ bias,
                                            float* __restrict__ out) {
    __shared__ __align__(16) short Cw[4608], Sw[4608], SwN[4608];
    __shared__ __align__(16) short A2C[2560], A2S[2560];
    __shared__ __align__(16) short Yr[2304], Yi[2304];   // [kh][72]
    __shared__ __align__(16) short ZTr[2560], ZTi[2560]; // Z transposed [w][40]
    const int tid = threadIdx.x;
    {
        const int4* src = (const int4*)cpool;
        for (int i = tid; i < 576; i += 256) {
            ((int4*)Cw)[i]  = src[i];
            ((int4*)Sw)[i]  = src[576 + i];
            ((int4*)SwN)[i] = src[1152 + i];
        }
        for (int i = tid; i < 320; i += 256) {
            ((int4*)A2C)[i] = src[1728 + i];
            ((int4*)A2S)[i] = src[2048 + i];
        }
    }
    for (int i = tid; i < 1152; i += 256) { ((int*)Yr)[i] = 0; ((int*)Yi)[i] = 0; }
    __syncthreads();
    const ushort2* yp = Yf + (size_t)blockIdx.x * NFH;
    for (int f = tid; f < NFH; f += 256) {
        int kh = f / 56, kw = f % 56;
        ushort2 v = yp[f];
        Yr[kh * 72 + kw] = (short)v.x;
        Yi[kh * 72 + kw] = (short)v.y;
    }
    __syncthreads();

    const int lane = tid & 63;
    const int nt = tid >> 6;
    const int q = lane >> 4, l15 = lane & 15;

    // ---- inv1: A = Y[kh][kw], B = (C + iS)[kw][w] via symmetry
    //      Zr = Yr*C - Yi*S ;  Zi = Yr*S + Yi*C
    f4v zr[2] = {}, zi[2] = {};
    for (int ks = 0; ks < 2; ++ks) {
        const int bo = (nt * 16 + l15) * 72 + ks * 32 + q * 8;
        s8v bC  = *(const s8v*)&Cw[bo];
        s8v bS  = *(const s8v*)&Sw[bo];
        s8v bSN = *(const s8v*)&SwN[bo];
        for (int mt = 0; mt < 2; ++mt) {
            const int ao = (mt * 16 + l15) * 72 + ks * 32 + q * 8;
            s8v ar = *(const s8v*)&Yr[ao];
            s8v ai = *(const s8v*)&Yi[ao];
            zr[mt] = MFMA(ar, bC, zr[mt]);
            zr[mt] = MFMA(ai, bSN, zr[mt]);
            zi[mt] = MFMA(ar, bS, zi[mt]);
            zi[mt] = MFMA(ai, bC, zi[mt]);
        }
    }
    for (int mt = 0; mt < 2; ++mt)
        for (int r = 0; r < 4; ++r) {
            int o = (nt * 16 + l15) * 40 + mt * 16 + q * 4 + r;  // [w][kh]
            ZTr[o] = f2bf(zr[mt][r]);
            ZTi[o] = f2bf(zi[mt][r]);
        }
    __syncthreads();

    // ---- inv2: A = A2C/A2S [h][kh] (K=32, one k-step), B = Z[kh][w]
    f4v yv[4] = {};
    {
        const int bo = (nt * 16 + l15) * 40 + q * 8;
        s8v br = *(const s8v*)&ZTr[bo];
        s8v bi = *(const s8v*)&ZTi[bo];
        for (int mt = 0; mt < 4; ++mt) {
            const int ao = (mt * 16 + l15) * 40 + q * 8;
            s8v ac  = *(const s8v*)&A2C[ao];
            s8v as_ = *(const s8v*)&A2S[ao];
            yv[mt] = MFMA(ac, br, yv[mt]);
            yv[mt] = MFMA(as_, bi, yv[mt]);
        }
    }
    const float bv = bias[blockIdx.x & (COUT - 1)];
    float* opx = out + (size_t)blockIdx.x * NF;
    const int w = nt * 16 + l15;
    if (w < 56) {
        for (int mt = 0; mt < 4; ++mt)
            for (int r = 0; r < 4; ++r) {
                int h = mt * 16 + q * 4 + r;
                if (h < 56) opx[h * 56 + w] = yv[mt][r] + bv;
            }
    }
}

// ---------------------------------------------------------------------------
extern "C" void kernel_launch(void* const* d_in, const int* in_sizes, int n_in,
                              void* d_out, int out_size, void* d_ws, size_t ws_size,
                              hipStream_t stream) {
    const float* x    = (const float*)d_in[0];
    const float* Kr   = (const float*)d_in[1];
    const float* Ki   = (const float*)d_in[2];
    const float* bias = (const float*)d_in[3];

    // Workspace layout (93.2 MB total):
    //   cpool  @0          : 40960 B constants
    //   Xb     @40960      : bf16 [B][CIN][1624]  ushort2   13,307,904 B
    //   Yb     @+13307904  : bf16 [B][COUT][1624] ushort2   26,615,808 B
    //   Kbr    @+26615808  : bf16 [1624][8192]               26,615,808 B
    //   Kbi    @+26615808  : bf16 [1624][8192]               26,615,808 B
    short*   cpool = (short*)d_ws;
    ushort2* Xb  = (ushort2*)((char*)d_ws + 40960);
    ushort2* Yb  = (ushort2*)((char*)d_ws + 40960 + 13307904);
    u16*     Kbr = (u16*)((char*)d_ws + 40960 + 13307904 + 26615808);
    u16*     Kbi = Kbr + (size_t)13307904;

    hipLaunchKernelGGL(ksetup, dim3(28), dim3(256), 0, stream, cpool);
    hipLaunchKernelGGL(kprep, dim3(128, 29), dim3(256), 0, stream, Kr, Ki, Kbr, Kbi);
    hipLaunchKernelGGL(kfwd, dim3(B * CIN), dim3(256), 0, stream, x, cpool, Xb);
    hipLaunchKernelGGL(kmix, dim3(NFH / 8), dim3(512), 0, stream, Xb, Kbr, Kbi, Yb);
    hipLaunchKernelGGL(kinv, dim3(B * COUT), dim3(256), 0, stream,
                       Yb, cpool, bias, (float*)d_out);
}

// Round 4
// 305.354 us; speedup vs baseline: 1.4372x; 1.1255x over previous
//
#include <hip/hip_runtime.h>

// FFT-conv: y = real(ifft2( sum_i K[o,i] * fft2(x[b,i]) )) + bias
// B=32, CIN=64, COUT=128, H=W=56.
// Hermitian symmetry: only spectral rows kh=0..28 stored (NFH=1624 bins).
// Pipeline:
//   kprep : K fp32 [o][i][f] -> bf16 planes [f][o][i]   (vectorized LDS transpose)
//   kfwd  : forward FFT2, 2 images / 512-thr block, bf16 MFMA
//   kmix  : per-bin complex channel mix as bf16 MFMA GEMM (M=32,N=128,K=64)
//   kinv  : inverse FFT2, 2 images / 512-thr block, bf16 MFMA
// SwN (-sin) plane eliminated from LDS: sign applied via bf16 sign-flip on
// the operand fragment (negbf) -> smaller LDS -> 16 waves/CU on kfwd/kinv.

#define HH 56
#define NF 3136      // 56*56
#define KH 29        // stored spectral rows
#define NFH 1624     // 29*56
constexpr int B = 32, CIN = 64, COUT = 128;
constexpr float PI2 = 6.283185307179586f;

typedef unsigned short u16;
typedef __attribute__((ext_vector_type(8))) short s8v;   // 8 x bf16 (A/B frag)
typedef __attribute__((ext_vector_type(4))) float f4v;   // C/D frag
typedef __attribute__((ext_vector_type(4))) int i4v;

#define MFMA(a, b, c) __builtin_amdgcn_mfma_f32_16x16x32_bf16(a, b, c, 0, 0, 0)

__device__ __host__ inline short f2bf(float f) {
    unsigned u = __builtin_bit_cast(unsigned, f);
    u += 0x7fffu + ((u >> 16) & 1u);      // round-to-nearest-even
    return (short)(u >> 16);
}

__device__ inline unsigned pk2(float a, float b) {   // pack 2 floats -> 2 bf16
    return (unsigned)(u16)f2bf(a) | ((unsigned)(u16)f2bf(b) << 16);
}

__device__ inline s8v negbf(s8v a) {       // flip bf16 sign bits
    i4v t = __builtin_bit_cast(i4v, a);
    t ^= (int)0x80008000u;
    return __builtin_bit_cast(s8v, t);
}

// ---------------------------------------------------------------------------
// Constant pool in d_ws (shorts):
//   Cw  [64][72] @0     : cos(2*pi*m*n/56), m<56&&n<56 else 0   (symmetric)
//   Sw  [64][72] @4608  : +sin(...)                             (symmetric)
//   (slot @9216 kept for layout compat, unused)
//   A2C [64][40] @13824 : wgt(kh)*cos(2*pi*h*kh/56)/3136  (h<56,kh<29 else 0)
//   A2S [64][40] @16384 : -wgt(kh)*sin(...)/3136
__global__ __launch_bounds__(256) void ksetup(short* __restrict__ cpool) {
    int i = blockIdx.x * 256 + threadIdx.x;
    if (i < 4608) {
        int m = i / 72, n = i % 72;
        float c = 0.f, s = 0.f;
        if (m < 56 && n < 56) {
            float ang = PI2 * (float)((m * n) % 56) / 56.f;
            c = cosf(ang); s = sinf(ang);
        }
        cpool[i]        = f2bf(c);
        cpool[4608 + i] = f2bf(s);
    } else if (i < 7168) {
        int j = i - 4608;
        int h = j / 40, kh = j % 40;
        float c = 0.f, s = 0.f;
        if (h < 56 && kh < 29) {
            float w = (kh == 0 || kh == 28) ? 1.f : 2.f;
            float ang = PI2 * (float)((h * kh) % 56) / 56.f;
            float sc = w * (1.f / 3136.f);
            c = sc * cosf(ang);
            s = -sc * sinf(ang);
        }
        cpool[13824 + j] = f2bf(c);
        cpool[16384 + j] = f2bf(s);
    }
}

// ---------------------------------------------------------------------------
// kprep: repack K spectrum fp32 [o][i][3136] (first 1624 bins used) into
// bf16 planes Kbr/Kbi [f][o*64+i]. float4 loads, packed uint2 LDS writes,
// uint2 global stores (4 j per store). LDS row stride 60 u16.
__global__ __launch_bounds__(256) void kprep(const float* __restrict__ Kr,
                                             const float* __restrict__ Ki,
                                             u16* __restrict__ Kbr,
                                             u16* __restrict__ Kbi) {
    __shared__ __align__(8) u16 Lr[64 * 60], Li[64 * 60];
    const int tid = threadIdx.x;
    const int oi0 = blockIdx.x * 64;   // 8192/64 = 128 tiles
    const int f0  = blockIdx.y * 56;   // 1624/56 = 29 tiles
    for (int c = tid; c < 896; c += 256) {        // 64 rows x 14 float4
        int row = c / 14, c4 = (c % 14) * 4;
        size_t g = (size_t)(oi0 + row) * NF + f0 + c4;
        float4 vr = *(const float4*)&Kr[g];
        float4 vi = *(const float4*)&Ki[g];
        *(uint2*)&Lr[row * 60 + c4] = make_uint2(pk2(vr.x, vr.y), pk2(vr.z, vr.w));
        *(uint2*)&Li[row * 60 + c4] = make_uint2(pk2(vi.x, vi.y), pk2(vi.z, vi.w));
    }
    __syncthreads();
    for (int idx = tid; idx < 896; idx += 256) {  // 56 f x 16 j-chunks
        int c = idx & 15, f = idx >> 4;
        int j0 = c * 4;
        unsigned r01 = (unsigned)Lr[j0 * 60 + f]       | ((unsigned)Lr[(j0 + 1) * 60 + f] << 16);
        unsigned r23 = (unsigned)Lr[(j0 + 2) * 60 + f] | ((unsigned)Lr[(j0 + 3) * 60 + f] << 16);
        unsigned i01 = (unsigned)Li[j0 * 60 + f]       | ((unsigned)Li[(j0 + 1) * 60 + f] << 16);
        unsigned i23 = (unsigned)Li[(j0 + 2) * 60 + f] | ((unsigned)Li[(j0 + 3) * 60 + f] << 16);
        size_t o = (size_t)(f0 + f) * 8192 + oi0 + j0;
        *(uint2*)&Kbr[o] = make_uint2(r01, r23);
        *(uint2*)&Kbi[o] = make_uint2(i01, i23);
    }
}

// ---------------------------------------------------------------------------
// kfwd: forward FFT2, 2 images per 512-thread block (waves 0-3 img0, 4-7 img1).
//   stage1: S1[h][kw]  = sum_w  x[h][w] * e^{-2pi i w kw/56}
//   stage2: X[kh][kw]  = sum_h  e^{-2pi i h kh/56} * S1[h][kw]   (kh<29 stored)
// Output: bf16 ushort2 (r,i) at [b*CIN+i][kh*56+kw].
__global__ __launch_bounds__(512) void kfwd(const float* __restrict__ x,
                                            const short* __restrict__ cpool,
                                            ushort2* __restrict__ Xb) {
    __shared__ __align__(16) short Cw[4608], Sw[4608];
    __shared__ __align__(16) short xs[2][4608];            // [h][72] bf16
    __shared__ __align__(16) short T1r[2][4608], T1i[2][4608]; // [kw][72]
    const int tid = threadIdx.x;
    {
        const int4* src = (const int4*)cpool;
        for (int i = tid; i < 576; i += 512) {
            ((int4*)Cw)[i] = src[i];
            ((int4*)Sw)[i] = src[576 + i];
        }
    }
    for (int i = tid; i < 4608; i += 512) ((int*)xs)[i] = 0;   // both images
    __syncthreads();
    const int half = tid >> 8, tid2 = tid & 255;
    const float* xp = x + (size_t)(blockIdx.x * 2 + half) * NF;
    short* xsh = xs[half];
    for (int c = tid2; c < 784; c += 256) {        // 56 rows x 14 float4
        int r = c / 14, c4 = (c % 14) * 4;
        float4 v = *(const float4*)&xp[r * 56 + c4];
        *(uint2*)&xsh[r * 72 + c4] = make_uint2(pk2(v.x, v.y), pk2(v.z, v.w));
    }
    __syncthreads();

    const int lane = tid & 63;
    const int wv = tid >> 6;
    const int hw = wv >> 2;            // image half (== tid>>8)
    const int nt = wv & 3;             // N-tile strip within image
    const int q = lane >> 4, l15 = lane & 15;

    // ---- stage 1: A = xs[h][w], B = (C - iS)[w][kw]  (B read via symmetry)
    f4v aR[4] = {}, aI[4] = {};
    for (int ks = 0; ks < 2; ++ks) {
        const int bo = (nt * 16 + l15) * 72 + ks * 32 + q * 8;
        s8v bC  = *(const s8v*)&Cw[bo];
        s8v bSN = negbf(*(const s8v*)&Sw[bo]);
        for (int mt = 0; mt < 4; ++mt) {
            s8v a = *(const s8v*)&xs[hw][(mt * 16 + l15) * 72 + ks * 32 + q * 8];
            aR[mt] = MFMA(a, bC, aR[mt]);
            aI[mt] = MFMA(a, bSN, aI[mt]);
        }
    }
    for (int mt = 0; mt < 4; ++mt) {
        int o = (nt * 16 + l15) * 72 + mt * 16 + q * 4;     // [kw][h]
        *(uint2*)&T1r[hw][o] = make_uint2(pk2(aR[mt][0], aR[mt][1]),
                                          pk2(aR[mt][2], aR[mt][3]));
        *(uint2*)&T1i[hw][o] = make_uint2(pk2(aI[mt][0], aI[mt][1]),
                                          pk2(aI[mt][2], aI[mt][3]));
    }
    __syncthreads();

    // ---- stage 2: A = (C2|S2)[kh][h] (top 32 rows of Cw/Sw), B = S1[h][kw]
    //      Xr = C2*S1r + S2*S1i ;  Xi = C2*S1i - S2*S1r
    f4v xr[2] = {}, xi2[2] = {};
    for (int ks = 0; ks < 2; ++ks) {
        const int bo = (nt * 16 + l15) * 72 + ks * 32 + q * 8;
        s8v br = *(const s8v*)&T1r[hw][bo];
        s8v bi = *(const s8v*)&T1i[hw][bo];
        for (int mt = 0; mt < 2; ++mt) {
            const int ao = (mt * 16 + l15) * 72 + ks * 32 + q * 8;
            s8v aC  = *(const s8v*)&Cw[ao];
            s8v aS  = *(const s8v*)&Sw[ao];
            s8v aSN = negbf(aS);
            xr[mt]  = MFMA(aC, br, xr[mt]);
            xr[mt]  = MFMA(aS, bi, xr[mt]);
            xi2[mt] = MFMA(aC, bi, xi2[mt]);
            xi2[mt] = MFMA(aSN, br, xi2[mt]);
        }
    }
    ushort2* op = Xb + (size_t)(blockIdx.x * 2 + hw) * NFH;
    const int kw = nt * 16 + l15;
    if (kw < 56) {
        for (int mt = 0; mt < 2; ++mt)
            for (int r = 0; r < 4; ++r) {
                int kh = mt * 16 + q * 4 + r;
                if (kh < 29)
                    op[kh * 56 + kw] = make_ushort2((u16)f2bf(xr[mt][r]),
                                                    (u16)f2bf(xi2[mt][r]));
            }
    }
}

// ---------------------------------------------------------------------------
// kmix: per-bin complex channel mix as bf16 MFMA GEMM.
//   Y[b][o](f) = sum_i X[b][i](f) * K[o][i](f)
// Block = 8 consecutive bins (grid 203), 512 threads = 8 waves.
// X staged once into padded LDS planes [8][32][72]; K B-frags read directly
// from global [f][o][i] planes (full-granule, fetched exactly once).
// Output packed bf16 in registers, one 32B-aligned burst per (b,o) row.
__global__ __launch_bounds__(512) void kmix(const ushort2* __restrict__ Xb,
                                            const u16* __restrict__ Kbr,
                                            const u16* __restrict__ Kbi,
                                            ushort2* __restrict__ Yb) {
    __shared__ __align__(16) u16 Xr[8 * 2304], Xi[8 * 2304];  // [f][b][72]
    const int tid = threadIdx.x;
    const int f0 = blockIdx.x * 8;

    // ---- stage X: 2048 (b,i) rows x 8 bins (2 x uint4 = 32B each)
    for (int rr = 0; rr < 4; ++rr) {
        int row = rr * 512 + tid;                       // b*64+i
        const uint4* src = (const uint4*)(Xb + (size_t)row * NFH + f0);
        uint4 v0 = src[0], v1 = src[1];
        int base = (row >> 6) * 72 + (row & 63);
        unsigned uu[8] = {v0.x, v0.y, v0.z, v0.w, v1.x, v1.y, v1.z, v1.w};
        #pragma unroll
        for (int ff = 0; ff < 8; ++ff) {
            Xr[ff * 2304 + base] = (u16)uu[ff];
            Xi[ff * 2304 + base] = (u16)(uu[ff] >> 16);
        }
    }
    __syncthreads();

    const int lane = tid & 63;
    const int wv = tid >> 6;            // wave = o-tile (8 x 16 = 128 outs)
    const int q = lane >> 4, l15 = lane & 15;

    unsigned pk[2][4][8];               // [mt][r][ff] packed (yr | yi<<16)

    #pragma unroll
    for (int ff = 0; ff < 8; ++ff) {
        const int f = f0 + ff;
        const size_t kb = (size_t)f * 8192 + (size_t)(wv * 16 + l15) * 64 + q * 8;
        s8v bkr0 = *(const s8v*)&Kbr[kb];
        s8v bkr1 = *(const s8v*)&Kbr[kb + 32];
        s8v bki0 = *(const s8v*)&Kbi[kb];
        s8v bki1 = *(const s8v*)&Kbi[kb + 32];

        f4v yr[2] = {}, yi[2] = {};
        #pragma unroll
        for (int mt = 0; mt < 2; ++mt) {
            const int ao = ff * 2304 + (mt * 16 + l15) * 72 + q * 8;
            s8v axr0 = *(const s8v*)&Xr[ao];
            s8v axr1 = *(const s8v*)&Xr[ao + 32];
            s8v axi0 = *(const s8v*)&Xi[ao];
            s8v axi1 = *(const s8v*)&Xi[ao + 32];
            s8v axn0 = negbf(axi0), axn1 = negbf(axi1);
            yr[mt] = MFMA(axr0, bkr0, yr[mt]);   // Yr = Xr*Kr - Xi*Ki
            yr[mt] = MFMA(axn0, bki0, yr[mt]);
            yr[mt] = MFMA(axr1, bkr1, yr[mt]);
            yr[mt] = MFMA(axn1, bki1, yr[mt]);
            yi[mt] = MFMA(axr0, bki0, yi[mt]);   // Yi = Xr*Ki + Xi*Kr
            yi[mt] = MFMA(axi0, bkr0, yi[mt]);
            yi[mt] = MFMA(axr1, bki1, yi[mt]);
            yi[mt] = MFMA(axi1, bkr1, yi[mt]);
        }
        #pragma unroll
        for (int mt = 0; mt < 2; ++mt)
            #pragma unroll
            for (int r = 0; r < 4; ++r)
                pk[mt][r][ff] = (unsigned)(u16)f2bf(yr[mt][r]) |
                                ((unsigned)(u16)f2bf(yi[mt][r]) << 16);
    }

    // ---- burst write: one 32B-aligned 32B run per (b,o) row
    const int o = wv * 16 + l15;
    #pragma unroll
    for (int mt = 0; mt < 2; ++mt)
        #pragma unroll
        for (int r = 0; r < 4; ++r) {
            const int b = mt * 16 + q * 4 + r;
            uint4* dst = (uint4*)(Yb + (size_t)(b * COUT + o) * NFH + f0);
            dst[0] = make_uint4(pk[mt][r][0], pk[mt][r][1],
                                pk[mt][r][2], pk[mt][r][3]);
            dst[1] = make_uint4(pk[mt][r][4], pk[mt][r][5],
                                pk[mt][r][6], pk[mt][r][7]);
        }
}

// ---------------------------------------------------------------------------
// kinv: inverse FFT2, 2 images per 512-thread block (waves 0-3 / 4-7).
//   inv1: Z[kh][w] = sum_kw Y[kh][kw] * e^{+2pi i kw w/56}
//   inv2: y[h][w]  = sum_kh wgt(kh)*(Zr*cos - Zi*sin)/3136 + bias
__global__ __launch_bounds__(512) void kinv(const ushort2* __restrict__ Yf,
                                            const short* __restrict__ cpool,
                                            const float* __restrict__ bias,
                                            float* __restrict__ out) {
    __shared__ __align__(16) short Cw[4608], Sw[4608];
    __shared__ __align__(16) short A2C[2560], A2S[2560];
    __shared__ __align__(16) short Yr[2][2304], Yi[2][2304];   // [kh][72]
    __shared__ __align__(16) short ZTr[2][2560], ZTi[2][2560]; // [w][40]
    const int tid = threadIdx.x;
    {
        const int4* src = (const int4*)cpool;
        for (int i = tid; i < 576; i += 512) {
            ((int4*)Cw)[i] = src[i];
            ((int4*)Sw)[i] = src[576 + i];
        }
        for (int i = tid; i < 320; i += 512) {
            ((int4*)A2C)[i] = src[1728 + i];
            ((int4*)A2S)[i] = src[2048 + i];
        }
    }
    for (int i = tid; i < 2304; i += 512) { ((int*)Yr)[i] = 0; ((int*)Yi)[i] = 0; }
    __syncthreads();
    const int half = tid >> 8, tid2 = tid & 255;
    const ushort2* yp = Yf + (size_t)(blockIdx.x * 2 + half) * NFH;
    for (int c = tid2; c < 406; c += 256) {        // 1624/4 uint4 chunks
        uint4 v = *(const uint4*)&yp[c * 4];
        int f = c * 4, kh = f / 56, kwb = f % 56;  // 56%4==0: no row crossing
        int o = kh * 72 + kwb;
        *(uint2*)&Yr[half][o] = make_uint2((v.x & 0xffffu) | (v.y << 16),
                                           (v.z & 0xffffu) | (v.w << 16));
        *(uint2*)&Yi[half][o] = make_uint2((v.x >> 16) | (v.y & 0xffff0000u),
                                           (v.z >> 16) | (v.w & 0xffff0000u));
    }
    __syncthreads();

    const int lane = tid & 63;
    const int wv = tid >> 6;
    const int hw = wv >> 2, nt = wv & 3;
    const int q = lane >> 4, l15 = lane & 15;

    // ---- inv1: A = Y[kh][kw], B = (C + iS)[kw][w] via symmetry
    //      Zr = Yr*C - Yi*S ;  Zi = Yr*S + Yi*C
    f4v zr[2] = {}, zi[2] = {};
    for (int ks = 0; ks < 2; ++ks) {
        const int bo = (nt * 16 + l15) * 72 + ks * 32 + q * 8;
        s8v bC = *(const s8v*)&Cw[bo];
        s8v bS = *(const s8v*)&Sw[bo];
        for (int mt = 0; mt < 2; ++mt) {
            const int ao = (mt * 16 + l15) * 72 + ks * 32 + q * 8;
            s8v ar  = *(const s8v*)&Yr[hw][ao];
            s8v ai  = *(const s8v*)&Yi[hw][ao];
            s8v ain = negbf(ai);
            zr[mt] = MFMA(ar, bC, zr[mt]);
            zr[mt] = MFMA(ain, bS, zr[mt]);
            zi[mt] = MFMA(ar, bS, zi[mt]);
            zi[mt] = MFMA(ai, bC, zi[mt]);
        }
    }
    for (int mt = 0; mt < 2; ++mt) {
        int o = (nt * 16 + l15) * 40 + mt * 16 + q * 4;      // [w][kh]
        *(uint2*)&ZTr[hw][o] = make_uint2(pk2(zr[mt][0], zr[mt][1]),
                                          pk2(zr[mt][2], zr[mt][3]));
        *(uint2*)&ZTi[hw][o] = make_uint2(pk2(zi[mt][0], zi[mt][1]),
                                          pk2(zi[mt][2], zi[mt][3]));
    }
    __syncthreads();

    // ---- inv2: A = A2C/A2S [h][kh] (K=32, one k-step), B = Z[kh][w]
    f4v yv[4] = {};
    {
        const int bo = (nt * 16 + l15) * 40 + q * 8;
        s8v br = *(const s8v*)&ZTr[hw][bo];
        s8v bi = *(const s8v*)&ZTi[hw][bo];
        for (int mt = 0; mt < 4; ++mt) {
            const int ao = (mt * 16 + l15) * 40 + q * 8;
            s8v ac  = *(const s8v*)&A2C[ao];
            s8v as_ = *(const s8v*)&A2S[ao];
            yv[mt] = MFMA(ac, br, yv[mt]);
            yv[mt] = MFMA(as_, bi, yv[mt]);
        }
    }
    const int img = blockIdx.x * 2 + hw;
    const float bv = bias[img & (COUT - 1)];
    float* opx = out + (size_t)img * NF;
    const int w = nt * 16 + l15;
    if (w < 56) {
        for (int mt = 0; mt < 4; ++mt)
            for (int r = 0; r < 4; ++r) {
                int h = mt * 16 + q * 4 + r;
                if (h < 56) opx[h * 56 + w] = yv[mt][r] + bv;
            }
    }
}

// ---------------------------------------------------------------------------
extern "C" void kernel_launch(void* const* d_in, const int* in_sizes, int n_in,
                              void* d_out, int out_size, void* d_ws, size_t ws_size,
                              hipStream_t stream) {
    const float* x    = (const float*)d_in[0];
    const float* Kr   = (const float*)d_in[1];
    const float* Ki   = (const float*)d_in[2];
    const float* bias = (const float*)d_in[3];

    // Workspace layout (93.2 MB total):
    //   cpool  @0          : 40960 B constants
    //   Xb     @40960      : bf16 [B][CIN][1624]  ushort2   13,307,904 B
    //   Yb     @+13307904  : bf16 [B][COUT][1624] ushort2   26,615,808 B
    //   Kbr/Kbi            : bf16 [1624][8192]  2 x 26,615,808 B
    short*   cpool = (short*)d_ws;
    ushort2* Xb  = (ushort2*)((char*)d_ws + 40960);
    ushort2* Yb  = (ushort2*)((char*)d_ws + 40960 + 13307904);
    u16*     Kbr = (u16*)((char*)d_ws + 40960 + 13307904 + 26615808);
    u16*     Kbi = Kbr + (size_t)13307904;

    hipLaunchKernelGGL(ksetup, dim3(28), dim3(256), 0, stream, cpool);
    hipLaunchKernelGGL(kprep, dim3(128, 29), dim3(256), 0, stream, Kr, Ki, Kbr, Kbi);
    hipLaunchKernelGGL(kfwd, dim3(B * CIN / 2), dim3(512), 0, stream, x, cpool, Xb);
    hipLaunchKernelGGL(kmix, dim3(NFH / 8), dim3(512), 0, stream, Xb, Kbr, Kbi, Yb);
    hipLaunchKernelGGL(kinv, dim3(B * COUT / 2), dim3(512), 0, stream,
                       Yb, cpool, bias, (float*)d_out);
}

// Round 6
// 302.750 us; speedup vs baseline: 1.4496x; 1.0086x over previous
//
#include <hip/hip_runtime.h>

// FFT-conv: y = real(ifft2( sum_i K[o,i] * fft2(x[b,i]) )) + bias
// B=32, CIN=64, COUT=128, H=W=56.
// Hermitian symmetry: only spectral rows kh=0..28 stored (NFH=1624 bins).
// Pipeline (3 worker dispatches after ksetup):
//   kstage : FUSED  [blocks 0..1023]   kfwd: forward FFT2, 2 images/block
//                   [blocks 1024..4735] kprep: K fp32 -> bf16 planes [f][o][i]
//            (independent producers for kmix -> overlap BW-bound kprep with
//             latency-bound kfwd in one dispatch)
//   kmix   : per-bin complex channel mix, bf16 MFMA GEMM, grid (203,2)
//            (o-dim split so grid 406 > 256 CUs)
//   kinv   : inverse FFT2, 2 images/block; ZT aliases dead Y region in LDS
//            -> 48 KB -> 3 blocks/CU

#define HH 56
#define NF 3136      // 56*56
#define KH 29        // stored spectral rows
#define NFH 1624     // 29*56
constexpr int B = 32, CIN = 64, COUT = 128;
constexpr float PI2 = 6.283185307179586f;

typedef unsigned short u16;
typedef __attribute__((ext_vector_type(8))) short s8v;   // 8 x bf16 (A/B frag)
typedef __attribute__((ext_vector_type(4))) float f4v;   // C/D frag
typedef __attribute__((ext_vector_type(4))) int i4v;

#define MFMA(a, b, c) __builtin_amdgcn_mfma_f32_16x16x32_bf16(a, b, c, 0, 0, 0)

__device__ __host__ inline short f2bf(float f) {
    unsigned u = __builtin_bit_cast(unsigned, f);
    u += 0x7fffu + ((u >> 16) & 1u);      // round-to-nearest-even
    return (short)(u >> 16);
}

__device__ inline unsigned pk2(float a, float b) {   // pack 2 floats -> 2 bf16
    return (unsigned)(u16)f2bf(a) | ((unsigned)(u16)f2bf(b) << 16);
}

__device__ inline s8v negbf(s8v a) {       // flip bf16 sign bits
    i4v t = __builtin_bit_cast(i4v, a);
    t ^= (int)0x80008000u;
    return __builtin_bit_cast(s8v, t);
}

// ---------------------------------------------------------------------------
// Constant pool in d_ws (shorts):
//   Cw  [64][72] @0     : cos(2*pi*m*n/56), m<56&&n<56 else 0   (symmetric)
//   Sw  [64][72] @4608  : +sin(...)                             (symmetric)
//   A2C [64][40] @13824 : wgt(kh)*cos(2*pi*h*kh/56)/3136  (h<56,kh<29 else 0)
//   A2S [64][40] @16384 : -wgt(kh)*sin(...)/3136
__global__ __launch_bounds__(256) void ksetup(short* __restrict__ cpool) {
    int i = blockIdx.x * 256 + threadIdx.x;
    if (i < 4608) {
        int m = i / 72, n = i % 72;
        float c = 0.f, s = 0.f;
        if (m < 56 && n < 56) {
            float ang = PI2 * (float)((m * n) % 56) / 56.f;
            c = cosf(ang); s = sinf(ang);
        }
        cpool[i]        = f2bf(c);
        cpool[4608 + i] = f2bf(s);
    } else if (i < 7168) {
        int j = i - 4608;
        int h = j / 40, kh = j % 40;
        float c = 0.f, s = 0.f;
        if (h < 56 && kh < 29) {
            float w = (kh == 0 || kh == 28) ? 1.f : 2.f;
            float ang = PI2 * (float)((h * kh) % 56) / 56.f;
            float sc = w * (1.f / 3136.f);
            c = sc * cosf(ang);
            s = -sc * sinf(ang);
        }
        cpool[13824 + j] = f2bf(c);
        cpool[16384 + j] = f2bf(s);
    }
}

// ---------------------------------------------------------------------------
// kstage: fused kfwd (blocks 0..1023) + kprep (blocks 1024..4735).
// 512 threads, 72 KB LDS union.
__global__ __launch_bounds__(512) void kstage(const float* __restrict__ x,
                                              const float* __restrict__ Kr,
                                              const float* __restrict__ Ki,
                                              const short* __restrict__ cpool,
                                              ushort2* __restrict__ Xb,
                                              u16* __restrict__ Kbr,
                                              u16* __restrict__ Kbi) {
    __shared__ __align__(16) char pool[73728];
    const int tid = threadIdx.x;

    if (blockIdx.x >= 1024) {
        // ================= kprep tile =================
        // repack K spectrum fp32 [o][i][3136] (first 1624 bins) into bf16
        // planes [f][o*64+i]. float4 loads, packed uint2 LDS writes,
        // uint2 global stores. LDS row stride 60 u16.
        u16* Lr = (u16*)pool;            // [64*60]
        u16* Li = Lr + 3840;
        const int t = blockIdx.x - 1024;           // 0..3711
        const int oi0 = (t & 127) * 64;            // 128 tiles over o*i
        const int f0  = (t >> 7) * 56;             // 29 tiles over f
        for (int c = tid; c < 896; c += 512) {     // 64 rows x 14 float4
            int row = c / 14, c4 = (c % 14) * 4;
            size_t g = (size_t)(oi0 + row) * NF + f0 + c4;
            float4 vr = *(const float4*)&Kr[g];
            float4 vi = *(const float4*)&Ki[g];
            *(uint2*)&Lr[row * 60 + c4] = make_uint2(pk2(vr.x, vr.y), pk2(vr.z, vr.w));
            *(uint2*)&Li[row * 60 + c4] = make_uint2(pk2(vi.x, vi.y), pk2(vi.z, vi.w));
        }
        __syncthreads();
        for (int idx = tid; idx < 896; idx += 512) {  // 56 f x 16 j-chunks
            int c = idx & 15, f = idx >> 4;
            int j0 = c * 4;
            unsigned r01 = (unsigned)Lr[j0 * 60 + f]       | ((unsigned)Lr[(j0 + 1) * 60 + f] << 16);
            unsigned r23 = (unsigned)Lr[(j0 + 2) * 60 + f] | ((unsigned)Lr[(j0 + 3) * 60 + f] << 16);
            unsigned i01 = (unsigned)Li[j0 * 60 + f]       | ((unsigned)Li[(j0 + 1) * 60 + f] << 16);
            unsigned i23 = (unsigned)Li[(j0 + 2) * 60 + f] | ((unsigned)Li[(j0 + 3) * 60 + f] << 16);
            size_t o = (size_t)(f0 + f) * 8192 + oi0 + j0;
            *(uint2*)&Kbr[o] = make_uint2(r01, r23);
            *(uint2*)&Kbi[o] = make_uint2(i01, i23);
        }
        return;
    }

    // ================= kfwd: 2 images per block =================
    //   stage1: S1[h][kw]  = sum_w  x[h][w] * e^{-2pi i w kw/56}
    //   stage2: X[kh][kw]  = sum_h  e^{-2pi i h kh/56} * S1[h][kw] (kh<29)
    short* Cw  = (short*)pool;          // [4608]
    short* Sw  = Cw + 4608;             // [4608]
    short* xs  = Sw + 4608;             // [2][4608]  [h][72]
    short* T1r = xs + 9216;             // [2][4608]  S1^T [kw][72]
    short* T1i = T1r + 9216;            // [2][4608]
    {
        const int4* src = (const int4*)cpool;
        for (int i = tid; i < 576; i += 512) {
            ((int4*)Cw)[i] = src[i];
            ((int4*)Sw)[i] = src[576 + i];
        }
    }
    for (int i = tid; i < 4608; i += 512) ((int*)xs)[i] = 0;   // both images
    __syncthreads();
    const int half = tid >> 8, tid2 = tid & 255;
    const float* xp = x + (size_t)(blockIdx.x * 2 + half) * NF;
    short* xsh = xs + half * 4608;
    for (int c = tid2; c < 784; c += 256) {        // 56 rows x 14 float4
        int r = c / 14, c4 = (c % 14) * 4;
        float4 v = *(const float4*)&xp[r * 56 + c4];
        *(uint2*)&xsh[r * 72 + c4] = make_uint2(pk2(v.x, v.y), pk2(v.z, v.w));
    }
    __syncthreads();

    const int lane = tid & 63;
    const int wv = tid >> 6;
    const int hw = wv >> 2;            // image half (== tid>>8)
    const int nt = wv & 3;             // N-tile strip within image
    const int q = lane >> 4, l15 = lane & 15;

    // ---- stage 1: A = xs[h][w], B = (C - iS)[w][kw]  (B read via symmetry)
    f4v aR[4] = {}, aI[4] = {};
    for (int ks = 0; ks < 2; ++ks) {
        const int bo = (nt * 16 + l15) * 72 + ks * 32 + q * 8;
        s8v bC  = *(const s8v*)&Cw[bo];
        s8v bSN = negbf(*(const s8v*)&Sw[bo]);
        for (int mt = 0; mt < 4; ++mt) {
            s8v a = *(const s8v*)&xs[hw * 4608 + (mt * 16 + l15) * 72 + ks * 32 + q * 8];
            aR[mt] = MFMA(a, bC, aR[mt]);
            aI[mt] = MFMA(a, bSN, aI[mt]);
        }
    }
    for (int mt = 0; mt < 4; ++mt) {
        int o = hw * 4608 + (nt * 16 + l15) * 72 + mt * 16 + q * 4;  // [kw][h]
        *(uint2*)&T1r[o] = make_uint2(pk2(aR[mt][0], aR[mt][1]),
                                      pk2(aR[mt][2], aR[mt][3]));
        *(uint2*)&T1i[o] = make_uint2(pk2(aI[mt][0], aI[mt][1]),
                                      pk2(aI[mt][2], aI[mt][3]));
    }
    __syncthreads();

    // ---- stage 2: A = (C2|S2)[kh][h] (top 32 rows of Cw/Sw), B = S1[h][kw]
    //      Xr = C2*S1r + S2*S1i ;  Xi = C2*S1i - S2*S1r
    f4v xr[2] = {}, xi2[2] = {};
    for (int ks = 0; ks < 2; ++ks) {
        const int bo = hw * 4608 + (nt * 16 + l15) * 72 + ks * 32 + q * 8;
        s8v br = *(const s8v*)&T1r[bo];
        s8v bi = *(const s8v*)&T1i[bo];
        for (int mt = 0; mt < 2; ++mt) {
            const int ao = (mt * 16 + l15) * 72 + ks * 32 + q * 8;
            s8v aC  = *(const s8v*)&Cw[ao];
            s8v aS  = *(const s8v*)&Sw[ao];
            s8v aSN = negbf(aS);
            xr[mt]  = MFMA(aC, br, xr[mt]);
            xr[mt]  = MFMA(aS, bi, xr[mt]);
            xi2[mt] = MFMA(aC, bi, xi2[mt]);
            xi2[mt] = MFMA(aSN, br, xi2[mt]);
        }
    }
    ushort2* op = Xb + (size_t)(blockIdx.x * 2 + hw) * NFH;
    const int kw = nt * 16 + l15;
    if (kw < 56) {
        for (int mt = 0; mt < 2; ++mt)
            for (int r = 0; r < 4; ++r) {
                int kh = mt * 16 + q * 4 + r;
                if (kh < 29)
                    op[kh * 56 + kw] = make_ushort2((u16)f2bf(xr[mt][r]),
                                                    (u16)f2bf(xi2[mt][r]));
            }
    }
}

// ---------------------------------------------------------------------------
// kmix: per-bin complex channel mix as bf16 MFMA GEMM.
//   Y[b][o](f) = sum_i X[b][i](f) * K[o][i](f)
// Grid (203, 2): block = 8 bins x 64 outs, 256 threads = 4 waves.
// X staged once into padded LDS planes [8][32][72]; K B-frags read directly
// from global [f][o][i] planes (full-granule, fetched exactly once).
// Output packed bf16 in registers, one 32B-aligned burst per (b,o) row.
__global__ __launch_bounds__(256) void kmix(const ushort2* __restrict__ Xb,
                                            const u16* __restrict__ Kbr,
                                            const u16* __restrict__ Kbi,
                                            ushort2* __restrict__ Yb) {
    __shared__ __align__(16) u16 Xr[8 * 2304], Xi[8 * 2304];  // [f][b][72]
    const int tid = threadIdx.x;
    const int f0 = blockIdx.x * 8;
    const int o0 = blockIdx.y * 64;

    // ---- stage X: 2048 (b,i) rows x 8 bins (2 x uint4 = 32B each)
    for (int rr = 0; rr < 8; ++rr) {
        int row = rr * 256 + tid;                       // b*64+i
        const uint4* src = (const uint4*)(Xb + (size_t)row * NFH + f0);
        uint4 v0 = src[0], v1 = src[1];
        int base = (row >> 6) * 72 + (row & 63);
        unsigned uu[8] = {v0.x, v0.y, v0.z, v0.w, v1.x, v1.y, v1.z, v1.w};
        #pragma unroll
        for (int ff = 0; ff < 8; ++ff) {
            Xr[ff * 2304 + base] = (u16)uu[ff];
            Xi[ff * 2304 + base] = (u16)(uu[ff] >> 16);
        }
    }
    __syncthreads();

    const int lane = tid & 63;
    const int wv = tid >> 6;            // wave = o-tile (4 x 16 = 64 outs)
    const int q = lane >> 4, l15 = lane & 15;
    const int o = o0 + wv * 16 + l15;

    unsigned pk[2][4][8];               // [mt][r][ff] packed (yr | yi<<16)

    #pragma unroll
    for (int ff = 0; ff < 8; ++ff) {
        const int f = f0 + ff;
        const size_t kb = (size_t)f * 8192 + (size_t)o * 64 + q * 8;
        s8v bkr0 = *(const s8v*)&Kbr[kb];
        s8v bkr1 = *(const s8v*)&Kbr[kb + 32];
        s8v bki0 = *(const s8v*)&Kbi[kb];
        s8v bki1 = *(const s8v*)&Kbi[kb + 32];

        f4v yr[2] = {}, yi[2] = {};
        #pragma unroll
        for (int mt = 0; mt < 2; ++mt) {
            const int ao = ff * 2304 + (mt * 16 + l15) * 72 + q * 8;
            s8v axr0 = *(const s8v*)&Xr[ao];
            s8v axr1 = *(const s8v*)&Xr[ao + 32];
            s8v axi0 = *(const s8v*)&Xi[ao];
            s8v axi1 = *(const s8v*)&Xi[ao + 32];
            s8v axn0 = negbf(axi0), axn1 = negbf(axi1);
            yr[mt] = MFMA(axr0, bkr0, yr[mt]);   // Yr = Xr*Kr - Xi*Ki
            yr[mt] = MFMA(axn0, bki0, yr[mt]);
            yr[mt] = MFMA(axr1, bkr1, yr[mt]);
            yr[mt] = MFMA(axn1, bki1, yr[mt]);
            yi[mt] = MFMA(axr0, bki0, yi[mt]);   // Yi = Xr*Ki + Xi*Kr
            yi[mt] = MFMA(axi0, bkr0, yi[mt]);
            yi[mt] = MFMA(axr1, bki1, yi[mt]);
            yi[mt] = MFMA(axi1, bkr1, yi[mt]);
        }
        #pragma unroll
        for (int mt = 0; mt < 2; ++mt)
            #pragma unroll
            for (int r = 0; r < 4; ++r)
                pk[mt][r][ff] = (unsigned)(u16)f2bf(yr[mt][r]) |
                                ((unsigned)(u16)f2bf(yi[mt][r]) << 16);
    }

    // ---- burst write: one 32B-aligned 32B run per (b,o) row
    #pragma unroll
    for (int mt = 0; mt < 2; ++mt)
        #pragma unroll
        for (int r = 0; r < 4; ++r) {
            const int b = mt * 16 + q * 4 + r;
            uint4* dst = (uint4*)(Yb + (size_t)(b * COUT + o) * NFH + f0);
            dst[0] = make_uint4(pk[mt][r][0], pk[mt][r][1],
                                pk[mt][r][2], pk[mt][r][3]);
            dst[1] = make_uint4(pk[mt][r][4], pk[mt][r][5],
                                pk[mt][r][6], pk[mt][r][7]);
        }
}

// ---------------------------------------------------------------------------
// kinv: inverse FFT2, 2 images per 512-thread block (waves 0-3 / 4-7).
//   inv1: Z[kh][w] = sum_kw Y[kh][kw] * e^{+2pi i kw w/56}
//   inv2: y[h][w]  = sum_kh wgt(kh)*(Zr*cos - Zi*sin)/3136 + bias
// LDS: ZT aliases the (dead after inv1) Y region -> 48 KB -> 3 blocks/CU.
__global__ __launch_bounds__(512) void kinv(const ushort2* __restrict__ Yf,
                                            const short* __restrict__ cpool,
                                            const float* __restrict__ bias,
                                            float* __restrict__ out) {
    __shared__ __align__(16) char pool[49152];
    short* Cw    = (short*)pool;        // [4608]
    short* Sw    = Cw + 4608;           // [4608]
    short* A2C   = Sw + 4608;           // [2560]
    short* A2S   = A2C + 2560;          // [2560]
    short* Ybase = A2S + 2560;          // 20480 B shared region
    short* Yr    = Ybase;               // [2][2304]  [kh][72]
    short* Yi    = Yr + 4608;
    short* ZTr   = Ybase;               // [2][2560]  [w][40]  (aliases Y)
    short* ZTi   = ZTr + 5120;
    const int tid = threadIdx.x;
    {
        const int4* src = (const int4*)cpool;
        for (int i = tid; i < 576; i += 512) {
            ((int4*)Cw)[i] = src[i];
            ((int4*)Sw)[i] = src[576 + i];
        }
        for (int i = tid; i < 320; i += 512) {
            ((int4*)A2C)[i] = src[1728 + i];
            ((int4*)A2S)[i] = src[2048 + i];
        }
    }
    for (int i = tid; i < 4608; i += 512) ((int*)Ybase)[i] = 0;  // Yr+Yi full
    __syncthreads();
    const int half = tid >> 8, tid2 = tid & 255;
    const ushort2* yp = Yf + (size_t)(blockIdx.x * 2 + half) * NFH;
    short* Yrh = Yr + half * 2304;
    short* Yih = Yi + half * 2304;
    for (int c = tid2; c < 406; c += 256) {        // 1624/4 uint4 chunks
        uint4 v = *(const uint4*)&yp[c * 4];
        int f = c * 4, kh = f / 56, kwb = f % 56;  // 56%4==0: no row crossing
        int o = kh * 72 + kwb;
        *(uint2*)&Yrh[o] = make_uint2((v.x & 0xffffu) | (v.y << 16),
                                      (v.z & 0xffffu) | (v.w << 16));
        *(uint2*)&Yih[o] = make_uint2((v.x >> 16) | (v.y & 0xffff0000u),
                                      (v.z >> 16) | (v.w & 0xffff0000u));
    }
    __syncthreads();

    const int lane = tid & 63;
    const int wv = tid >> 6;
    const int hw = wv >> 2, nt = wv & 3;
    const int q = lane >> 4, l15 = lane & 15;

    // ---- inv1: A = Y[kh][kw], B = (C + iS)[kw][w] via symmetry
    //      Zr = Yr*C - Yi*S ;  Zi = Yr*S + Yi*C
    f4v zr[2] = {}, zi[2] = {};
    for (int ks = 0; ks < 2; ++ks) {
        const int bo = (nt * 16 + l15) * 72 + ks * 32 + q * 8;
        s8v bC = *(const s8v*)&Cw[bo];
        s8v bS = *(const s8v*)&Sw[bo];
        for (int mt = 0; mt < 2; ++mt) {
            const int ao = hw * 2304 + (mt * 16 + l15) * 72 + ks * 32 + q * 8;
            s8v ar  = *(const s8v*)&Yr[ao];
            s8v ai  = *(const s8v*)&Yi[ao];
            s8v ain = negbf(ai);
            zr[mt] = MFMA(ar, bC, zr[mt]);
            zr[mt] = MFMA(ain, bS, zr[mt]);
            zi[mt] = MFMA(ar, bS, zi[mt]);
            zi[mt] = MFMA(ai, bC, zi[mt]);
        }
    }
    __syncthreads();   // Y region dead; ZT aliases it
    for (int mt = 0; mt < 2; ++mt) {
        int o = hw * 2560 + (nt * 16 + l15) * 40 + mt * 16 + q * 4;  // [w][kh]
        *(uint2*)&ZTr[o] = make_uint2(pk2(zr[mt][0], zr[mt][1]),
                                      pk2(zr[mt][2], zr[mt][3]));
        *(uint2*)&ZTi[o] = make_uint2(pk2(zi[mt][0], zi[mt][1]),
                                      pk2(zi[mt][2], zi[mt][3]));
    }
    __syncthreads();

    // ---- inv2: A = A2C/A2S [h][kh] (K=32, one k-step), B = Z[kh][w]
    f4v yv[4] = {};
    {
        const int bo = hw * 2560 + (nt * 16 + l15) * 40 + q * 8;
        s8v br = *(const s8v*)&ZTr[bo];
        s8v bi = *(const s8v*)&ZTi[bo];
        for (int mt = 0; mt < 4; ++mt) {
            const int ao = (mt * 16 + l15) * 40 + q * 8;
            s8v ac  = *(const s8v*)&A2C[ao];
            s8v as_ = *(const s8v*)&A2S[ao];
            yv[mt] = MFMA(ac, br, yv[mt]);
            yv[mt] = MFMA(as_, bi, yv[mt]);
        }
    }
    const int img = blockIdx.x * 2 + hw;
    const float bv = bias[img & (COUT - 1)];
    float* opx = out + (size_t)img * NF;
    const int w = nt * 16 + l15;
    if (w < 56) {
        for (int mt = 0; mt < 4; ++mt)
            for (int r = 0; r < 4; ++r) {
                int h = mt * 16 + q * 4 + r;
                if (h < 56) opx[h * 56 + w] = yv[mt][r] + bv;
            }
    }
}

// ---------------------------------------------------------------------------
extern "C" void kernel_launch(void* const* d_in, const int* in_sizes, int n_in,
                              void* d_out, int out_size, void* d_ws, size_t ws_size,
                              hipStream_t stream) {
    const float* x    = (const float*)d_in[0];
    const float* Kr   = (const float*)d_in[1];
    const float* Ki   = (const float*)d_in[2];
    const float* bias = (const float*)d_in[3];

    // Workspace layout (93.2 MB total):
    //   cpool  @0          : 40960 B constants
    //   Xb     @40960      : bf16 [B][CIN][1624]  ushort2   13,307,904 B
    //   Yb     @+13307904  : bf16 [B][COUT][1624] ushort2   26,615,808 B
    //   Kbr/Kbi            : bf16 [1624][8192]  2 x 26,615,808 B
    short*   cpool = (short*)d_ws;
    ushort2* Xb  = (ushort2*)((char*)d_ws + 40960);
    ushort2* Yb  = (ushort2*)((char*)d_ws + 40960 + 13307904);
    u16*     Kbr = (u16*)((char*)d_ws + 40960 + 13307904 + 26615808);
    u16*     Kbi = Kbr + (size_t)13307904;

    hipLaunchKernelGGL(ksetup, dim3(28), dim3(256), 0, stream, cpool);
    // fused: blocks [0,1024) = kfwd (2 img each), [1024,4736) = kprep tiles
    hipLaunchKernelGGL(kstage, dim3(1024 + 3712), dim3(512), 0, stream,
                       x, Kr, Ki, cpool, Xb, Kbr, Kbi);
    hipLaunchKernelGGL(kmix, dim3(NFH / 8, 2), dim3(256), 0, stream,
                       Xb, Kbr, Kbi, Yb);
    hipLaunchKernelGGL(kinv, dim3(B * COUT / 2), dim3(512), 0, stream,
                       Yb, cpool, bias, (float*)d_out);
}